// Round 7
// baseline (448.842 us; speedup 1.0000x reference)
//
#include <hip/hip_runtime.h>
#include <hip/hip_cooperative_groups.h>
#include <math.h>

namespace cg = cooperative_groups;

#define D 64
#define MAXNORM 0.999f
#define MAXNORM2 (0.999f * 0.999f)
#define MIN_NORM 1e-15f
#define TANH_CLIP 15.0f
#define CHUNK 1024

struct f4 { float x, y, z, w; };

__device__ __forceinline__ float frcp(float x) { return __builtin_amdgcn_rcpf(x); }
__device__ __forceinline__ float frsq(float x) { return __builtin_amdgcn_rsqf(x); }

__device__ __forceinline__ float dot8p(const f4& a0, const f4& a1,
                                       const f4& b0, const f4& b1) {
    return a0.x * b0.x + a0.y * b0.y + a0.z * b0.z + a0.w * b0.w +
           a1.x * b1.x + a1.y * b1.y + a1.z * b1.z + a1.w * b1.w;
}

__device__ __forceinline__ float rsum8(float v) {
    v += __shfl_xor(v, 1);
    v += __shfl_xor(v, 2);
    v += __shfl_xor(v, 4);
    return v;
}

// One cooperative kernel, 5 phases separated by grid syncs:
// P0 zero cnt | P1 hist+rank+norms | P2 scan | P3 scatter | P4 agg (persistent)
__global__ void __launch_bounds__(256) mega_kernel(
        const float* __restrict__ ego,
        const float* __restrict__ rel,
        const int* __restrict__ eidx,
        const int* __restrict__ etyp,
        float* __restrict__ out,
        int* __restrict__ cnt,
        int* __restrict__ off,
        int* __restrict__ rank,
        int* __restrict__ sorted,
        float* __restrict__ norms,
        float* __restrict__ relnorm,
        int N, int E, int NB) {
    cg::grid_group grid = cg::this_grid();
    __shared__ int sdata[256];
    __shared__ int sprefix;

    const int tid     = threadIdx.x;
    const int gthread = blockIdx.x * 256 + tid;
    const int gsize   = gridDim.x * 256;
    const int lane    = tid & 63;
    const int gwave   = gthread >> 6;
    const int nwave   = gsize >> 6;

    // ---- P0: zero cnt ----
    for (int i = gthread; i < N; i += gsize) cnt[i] = 0;
    grid.sync();

    // ---- P1: histogram + per-edge rank; row norms ----
    for (int e = gthread; e < E; e += gsize)
        rank[e] = atomicAdd(&cnt[eidx[e]], 1);
    for (int w = gwave; w < N + 32; w += nwave) {
        const float* src = (w < N) ? (ego + (size_t)w * D)
                                   : (rel + (size_t)(w - N) * D);
        float v = src[lane];
        float s = v * v;
        s += __shfl_xor(s, 1);  s += __shfl_xor(s, 2);  s += __shfl_xor(s, 4);
        s += __shfl_xor(s, 8);  s += __shfl_xor(s, 16); s += __shfl_xor(s, 32);
        if (lane == 0) {
            if (w < N) norms[w] = sqrtf(s);
            else       relnorm[w - N] = sqrtf(s);
        }
    }
    grid.sync();

    // ---- P2: exclusive scan of cnt -> off (blocks 0..NB-1) ----
    if (blockIdx.x < NB) {
        int base0 = blockIdx.x * CHUNK;
        int psum = 0;
        const int4* cnt4 = (const int4*)cnt;
        for (int i = tid; i < (base0 >> 2); i += 256) {
            int4 v = cnt4[i];
            psum += v.x + v.y + v.z + v.w;
        }
        sdata[tid] = psum;
        __syncthreads();
        for (int o = 128; o > 0; o >>= 1) {
            if (tid < o) sdata[tid] += sdata[tid + o];
            __syncthreads();
        }
        if (tid == 0) sprefix = sdata[0];
        __syncthreads();
        int prefix = sprefix;
        __syncthreads();

        int base = base0 + tid * 4;
        int v0 = (base + 0 < N) ? cnt[base + 0] : 0;
        int v1 = (base + 1 < N) ? cnt[base + 1] : 0;
        int v2 = (base + 2 < N) ? cnt[base + 2] : 0;
        int v3 = (base + 3 < N) ? cnt[base + 3] : 0;
        sdata[tid] = v0 + v1 + v2 + v3;
        __syncthreads();
        for (int o = 1; o < 256; o <<= 1) {
            int add = (tid >= o) ? sdata[tid - o] : 0;
            __syncthreads();
            sdata[tid] += add;
            __syncthreads();
        }
        int run = prefix + ((tid > 0) ? sdata[tid - 1] : 0);
        if (base + 0 < N) { off[base + 0] = run; run += v0; }
        if (base + 1 < N) { off[base + 1] = run; run += v1; }
        if (base + 2 < N) { off[base + 2] = run; run += v2; }
        if (base + 3 < N) { off[base + 3] = run; run += v3; }
    }
    grid.sync();

    // ---- P3: atomic-free scatter: pos = off[head] + rank ----
    for (int e = gthread; e < E; e += gsize) {
        int pos = off[eidx[e]] + rank[e];
        sorted[pos] = eidx[E + e] | (etyp[e] << 17);
    }
    grid.sync();

    // ---- P4: segmented aggregation, persistent: one wave per head ----
    // Per-edge geometry is scalar algebra over 3 dots (h.t, h.r, t.r); norms
    // of Mobius sums via |x(+)y|^2 = (|x|^2 + 2 x.y + |y|^2) * inv_den.
    {
        const int slot = lane >> 3;   // 8 edge-slots per wave
        const int sub  = lane & 7;    // 8 lanes per edge, 8 comps each

        for (int h = gwave; h < N; h += nwave) {
            const float* hrow = ego + (size_t)h * D + sub * 8;
            f4 h0 = *(const f4*)(hrow);
            f4 h1 = *(const f4*)(hrow + 4);

            float nh  = fmaxf(norms[h], MIN_NORM);
            float xh  = fminf(nh, TANH_CLIP);
            float eh  = __expf(-2.0f * xh);
            float fp  = (1.0f - eh) * frcp((1.0f + eh) * nh);   // p = fp*h
            float p2  = fp * fp * nh * nh;                      // tanh(nh)^2
            float tol = fmaxf(1.0f - p2, MIN_NORM);             // 2/lam
            float hl  = frcp(tol);                              // 0.5*lam

            int o = off[h];
            int c = cnt[h];
            f4 a0 = {0.f, 0.f, 0.f, 0.f}, a1 = {0.f, 0.f, 0.f, 0.f};
            float accP = 0.f;

            int i = slot;
            int pk = (i < c) ? sorted[o + i] : 0;     // prefetched payload
            for (; i < c; i += 8) {
                int inext = i + 8;
                int pkn = (inext < c) ? sorted[o + inext] : 0;

                int tail = pk & 0x1FFFF;
                int type = pk >> 17;

                const float* trow = ego + (size_t)tail * D + sub * 8;
                f4 t0 = *(const f4*)(trow);
                f4 t1 = *(const f4*)(trow + 4);
                const float* rrow = rel + (size_t)type * D + sub * 8;
                f4 r0 = *(const f4*)(rrow);
                f4 r1 = *(const f4*)(rrow + 4);
                float nt = norms[tail];
                float nr = relnorm[type];

                // the only 3 wave reductions per edge
                float d_ht = rsum8(dot8p(h0, h1, t0, t1));
                float d_hr = rsum8(dot8p(h0, h1, r0, r1));
                float d_tr = rsum8(dot8p(t0, t1, r0, r1));

                float t2 = nt * nt, r2 = nr * nr;
                float pt = fp * d_ht;
                float pr = fp * d_hr;

                // hyper_tail = p (+) ft*t
                float ntc = fmaxf(nt, MIN_NORM);
                float xt  = fminf(hl * ntc, TANH_CLIP);
                float et  = __expf(-2.0f * xt);
                float ft  = (1.0f - et) * frcp((1.0f + et) * ntc);
                float yt2 = ft * ft * t2;
                float pyt = ft * pt;
                float invt = frcp(fmaxf(1.0f + 2.0f * pyt + p2 * yt2, MIN_NORM));
                float At = (1.0f + 2.0f * pyt + yt2) * invt;
                float Bt = tol * invt * ft;
                float x2 = (p2 + 2.0f * pyt + yt2) * invt;   // |ht|^2

                // hyper_rel = p (+) fr*r
                float nrc = fmaxf(nr, MIN_NORM);
                float xr  = fminf(hl * nrc, TANH_CLIP);
                float er  = __expf(-2.0f * xr);
                float fr  = (1.0f - er) * frcp((1.0f + er) * nrc);
                float yr2 = fr * fr * r2;
                float pyr = fr * pr;
                float invr = frcp(fmaxf(1.0f + 2.0f * pyr + p2 * yr2, MIN_NORM));
                float Ar = (1.0f + 2.0f * pyr + yr2) * invr;
                float Br = tol * invr * fr;
                float y2 = (p2 + 2.0f * pyr + yr2) * invr;   // |hr|^2

                // m = ht (+) hr
                float xy = At * Ar * p2 + At * Br * pr + Ar * Bt * pt + Bt * Br * d_tr;
                float am = 1.0f + 2.0f * xy + y2;
                float bm = 1.0f - x2;
                float invm = frcp(fmaxf(1.0f + 2.0f * xy + x2 * y2, MIN_NORM));
                float al = (am * At + bm * Ar) * invm;
                float be = am * Bt * invm;
                float ga = bm * Br * invm;
                float m2 = (x2 + 2.0f * xy + y2) * invm;     // |m|^2
                m2 = fmaxf(m2, 1e-30f);

                // project
                float scp = (m2 > MAXNORM2) ? MAXNORM * frsq(m2) : 1.0f;
                al *= scp; be *= scp; ga *= scp;
                m2 *= scp * scp;

                // s = (-p) (+) m
                float pm   = al * p2 + be * pt + ga * pr;
                float invs = frcp(fmaxf(1.0f - 2.0f * pm + p2 * m2, MIN_NORM));
                float sp   = -(1.0f - 2.0f * pm + m2) * invs;
                float smm  = tol * invs;
                float u = sp + smm * al;
                float v = smm * be;
                float w = smm * ga;
                float s2 = (p2 - 2.0f * pm + m2) * invs;     // |s|^2
                s2 = fmaxf(s2, 1e-30f);

                float irs = frsq(s2);
                float ns  = fminf(s2 * irs, 1.0f - 1e-7f);
                float art = 0.5f * __logf((1.0f + ns) * frcp(1.0f - ns));
                float sc  = tol * art * irs;

                float ct = sc * v, cr = sc * w;
                accP += sc * u;
                a0.x += ct * t0.x + cr * r0.x;  a0.y += ct * t0.y + cr * r0.y;
                a0.z += ct * t0.z + cr * r0.z;  a0.w += ct * t0.w + cr * r0.w;
                a1.x += ct * t1.x + cr * r1.x;  a1.y += ct * t1.y + cr * r1.y;
                a1.z += ct * t1.z + cr * r1.z;  a1.w += ct * t1.w + cr * r1.w;

                pk = pkn;
            }

            // reduce the 8 slots (lanes l, l^8, l^16, l^32)
            #define RED(x) x += __shfl_xor(x, 8); x += __shfl_xor(x, 16); x += __shfl_xor(x, 32);
            RED(accP)
            RED(a0.x) RED(a0.y) RED(a0.z) RED(a0.w)
            RED(a1.x) RED(a1.y) RED(a1.z) RED(a1.w)
            #undef RED

            if (slot == 0) {
                float invc = frcp(fmaxf((float)c, 1.0f));
                float hp = accP * fp * invc;
                f4 o0, o1;
                o0.x = hp * h0.x + a0.x * invc;  o0.y = hp * h0.y + a0.y * invc;
                o0.z = hp * h0.z + a0.z * invc;  o0.w = hp * h0.w + a0.w * invc;
                o1.x = hp * h1.x + a1.x * invc;  o1.y = hp * h1.y + a1.y * invc;
                o1.z = hp * h1.z + a1.z * invc;  o1.w = hp * h1.w + a1.w * invc;
                float* orow = out + (size_t)h * D + sub * 8;
                *(f4*)(orow)     = o0;
                *(f4*)(orow + 4) = o1;
            }
        }
    }
}

extern "C" void kernel_launch(void* const* d_in, const int* in_sizes, int n_in,
                              void* d_out, int out_size, void* d_ws, size_t ws_size,
                              hipStream_t stream) {
    const float* ego  = (const float*)d_in[0];
    const int*   eidx = (const int*)d_in[1];
    const int*   etyp = (const int*)d_in[2];
    const float* rel  = (const float*)d_in[3];
    float* out = (float*)d_out;

    int E = in_sizes[1] / 2;          // 800000
    int N = in_sizes[0] / D;          // 100000
    int NB = (N + CHUNK - 1) / CHUNK; // 98

    // workspace layout (~7.6 MB)
    int* cnt      = (int*)d_ws;           // N
    int* off      = cnt + N;              // N
    int* rank     = off + N;              // E
    int* sorted   = rank + E;             // E
    float* norms   = (float*)(sorted + E);     // N
    float* relnorm = norms + N;                // 32

    // size grid to guaranteed co-residency (cooperative launch requirement)
    int blocksPerCU = 0;
    hipOccupancyMaxActiveBlocksPerMultiprocessor(&blocksPerCU, mega_kernel, 256, 0);
    if (blocksPerCU < 1) blocksPerCU = 1;
    long long g = (long long)blocksPerCU * 256;   // 256 CUs on MI355X
    if (g > 2048) g = 2048;
    if (g < NB)   g = NB;
    int grid = (int)g;

    void* args[] = { (void*)&ego, (void*)&rel, (void*)&eidx, (void*)&etyp,
                     (void*)&out, (void*)&cnt, (void*)&off, (void*)&rank,
                     (void*)&sorted, (void*)&norms, (void*)&relnorm,
                     (void*)&N, (void*)&E, (void*)&NB };
    hipLaunchCooperativeKernel(mega_kernel, dim3(grid), dim3(256), args, 0, stream);
}

// Round 8
// 171.554 us; speedup vs baseline: 2.6163x; 2.6163x over previous
//
#include <hip/hip_runtime.h>
#include <math.h>

#define D 64
#define MAXNORM 0.999f
#define MAXNORM2 (0.999f * 0.999f)
#define MIN_NORM 1e-15f
#define TANH_CLIP 15.0f
#define CHUNK 1024

struct f4 { float x, y, z, w; };

__device__ __forceinline__ float frcp(float x) { return __builtin_amdgcn_rcpf(x); }
__device__ __forceinline__ float frsq(float x) { return __builtin_amdgcn_rsqf(x); }

__device__ __forceinline__ float dot8p(const f4& a0, const f4& a1,
                                       const f4& b0, const f4& b1) {
    return a0.x * b0.x + a0.y * b0.y + a0.z * b0.z + a0.w * b0.w +
           a1.x * b1.x + a1.y * b1.y + a1.z * b1.z + a1.w * b1.w;
}

__device__ __forceinline__ float rsum8(float v) {
    v += __shfl_xor(v, 1);
    v += __shfl_xor(v, 2);
    v += __shfl_xor(v, 4);
    return v;
}

// ------- histogram + per-edge rank -------

__global__ void hist_kernel(const int* __restrict__ eidx,
                            int* __restrict__ cnt,
                            int* __restrict__ rank, int E) {
    int e = blockIdx.x * blockDim.x + threadIdx.x;
    if (e < E) rank[e] = atomicAdd(&cnt[eidx[e]], 1);
}

// ------- single-kernel scan (blocks [0,NB)) + row norms (blocks [NB,..)) -------

__global__ void scan_kernel(const int* __restrict__ cnt,
                            int* __restrict__ off,
                            const float* __restrict__ ego,
                            const float* __restrict__ rel,
                            float* __restrict__ norms,
                            float* __restrict__ relnorm,
                            int N, int NB) {
    if (blockIdx.x >= NB) {
        // ---- norm part: one wave per row ----
        int wid = (blockIdx.x - NB) * 4 + (threadIdx.x >> 6);
        int lane = threadIdx.x & 63;
        const float* src;
        float* dst;
        if (wid < N)            { src = ego + (size_t)wid * D;       dst = norms + wid; }
        else if (wid < N + 32)  { src = rel + (size_t)(wid - N) * D; dst = relnorm + (wid - N); }
        else return;
        float v = src[lane];
        float s = v * v;
        s += __shfl_xor(s, 1);  s += __shfl_xor(s, 2);  s += __shfl_xor(s, 4);
        s += __shfl_xor(s, 8);  s += __shfl_xor(s, 16); s += __shfl_xor(s, 32);
        if (lane == 0) *dst = sqrtf(s);
        return;
    }

    __shared__ int sdata[256];
    __shared__ int sprefix;
    int tid = threadIdx.x;
    int base0 = blockIdx.x * CHUNK;

    // phase A: prefix = sum of cnt[0..base0)
    int psum = 0;
    const int4* cnt4 = (const int4*)cnt;
    for (int i = tid; i < (base0 >> 2); i += 256) {
        int4 v = cnt4[i];
        psum += v.x + v.y + v.z + v.w;
    }
    sdata[tid] = psum;
    __syncthreads();
    for (int o = 128; o > 0; o >>= 1) {
        if (tid < o) sdata[tid] += sdata[tid + o];
        __syncthreads();
    }
    if (tid == 0) sprefix = sdata[0];
    __syncthreads();
    int prefix = sprefix;
    __syncthreads();

    // phase B: scan own 1024-entry chunk
    int base = base0 + tid * 4;
    int v0 = (base + 0 < N) ? cnt[base + 0] : 0;
    int v1 = (base + 1 < N) ? cnt[base + 1] : 0;
    int v2 = (base + 2 < N) ? cnt[base + 2] : 0;
    int v3 = (base + 3 < N) ? cnt[base + 3] : 0;
    sdata[tid] = v0 + v1 + v2 + v3;
    __syncthreads();
    for (int o = 1; o < 256; o <<= 1) {
        int add = (tid >= o) ? sdata[tid - o] : 0;
        __syncthreads();
        sdata[tid] += add;
        __syncthreads();
    }
    int run = prefix + ((tid > 0) ? sdata[tid - 1] : 0);
    if (base + 0 < N) { off[base + 0] = run; run += v0; }
    if (base + 1 < N) { off[base + 1] = run; run += v1; }
    if (base + 2 < N) { off[base + 2] = run; run += v2; }
    if (base + 3 < N) { off[base + 3] = run; run += v3; }
}

// atomic-free scatter: pos = off[head] + rank[e]; payload = tail | type<<17
__global__ void scatter_kernel(const int* __restrict__ eidx,
                               const int* __restrict__ etype,
                               const int* __restrict__ rank,
                               const int* __restrict__ off,
                               int* __restrict__ sorted, int E) {
    int e = blockIdx.x * blockDim.x + threadIdx.x;
    if (e < E) {
        int pos = off[eidx[e]] + rank[e];
        sorted[pos] = eidx[E + e] | (etype[e] << 17);
    }
}

// ---------------- segmented aggregation: one wave per head ----------------
// Per-edge geometry is scalar algebra over 3 dots (h.t, h.r, t.r); norms of
// Mobius sums via |x(+)y|^2 = (|x|^2 + 2 x.y + |y|^2) * inv_den.
// 2-stage software pipeline: next edge's payload + rows prefetched into
// registers while the current ~400-cycle scalar chain executes.

__global__ void __launch_bounds__(256, 4) agg_kernel(
        const float* __restrict__ ego,
        const float* __restrict__ rel,
        const int* __restrict__ off,
        const int* __restrict__ cnt,
        const int* __restrict__ sorted,
        const float* __restrict__ norms,
        const float* __restrict__ relnorm,
        float* __restrict__ out,
        int N) {
    int wid = (blockIdx.x * blockDim.x + threadIdx.x) >> 6;   // one wave per head
    if (wid >= N) return;
    int lane = threadIdx.x & 63;
    int slot = lane >> 3;     // 8 edge-slots per wave
    int sub  = lane & 7;      // 8 lanes per edge, 8 comps each

    int h = wid;
    const float* hrow = ego + (size_t)h * D + sub * 8;
    f4 h0 = *(const f4*)(hrow);
    f4 h1 = *(const f4*)(hrow + 4);

    // head-only scalars
    float nh  = fmaxf(norms[h], MIN_NORM);
    float xh  = fminf(nh, TANH_CLIP);
    float eh  = __expf(-2.0f * xh);
    float fp  = (1.0f - eh) * frcp((1.0f + eh) * nh);   // p = fp * h
    float p2  = fp * fp * nh * nh;                      // tanh(nh)^2
    float tol = fmaxf(1.0f - p2, MIN_NORM);             // 2/lam
    float hl  = frcp(tol);                              // 0.5*lam

    int o = off[h];
    int c = cnt[h];
    f4 a0 = {0.f, 0.f, 0.f, 0.f}, a1 = {0.f, 0.f, 0.f, 0.f};
    float accP = 0.f;

    // ---- pipeline stage 0: load first edge ----
    int i = slot;
    bool act = (i < c);
    f4 t0, t1, r0, r1;
    float nt = 1.0f, nr = 1.0f;
    if (act) {
        int pk   = sorted[o + i];
        int tail = pk & 0x1FFFF;
        int type = pk >> 17;
        const float* trow = ego + (size_t)tail * D + sub * 8;
        t0 = *(const f4*)(trow);
        t1 = *(const f4*)(trow + 4);
        const float* rrow = rel + (size_t)type * D + sub * 8;
        r0 = *(const f4*)(rrow);
        r1 = *(const f4*)(rrow + 4);
        nt = norms[tail];
        nr = relnorm[type];
    }

    while (act) {
        // ---- prefetch next edge (in flight during the chain below) ----
        int inext = i + 8;
        bool actn = (inext < c);
        f4 pt0, pt1, pr0, pr1;
        float ntn = 1.0f, nrn = 1.0f;
        if (actn) {
            int pkn   = sorted[o + inext];
            int tailn = pkn & 0x1FFFF;
            int typen = pkn >> 17;
            const float* trown = ego + (size_t)tailn * D + sub * 8;
            pt0 = *(const f4*)(trown);
            pt1 = *(const f4*)(trown + 4);
            const float* rrown = rel + (size_t)typen * D + sub * 8;
            pr0 = *(const f4*)(rrown);
            pr1 = *(const f4*)(rrown + 4);
            ntn = norms[tailn];
            nrn = relnorm[typen];
        }

        // ---- the only 3 wave reductions per edge ----
        float d_ht = rsum8(dot8p(h0, h1, t0, t1));
        float d_hr = rsum8(dot8p(h0, h1, r0, r1));
        float d_tr = rsum8(dot8p(t0, t1, r0, r1));

        float t2 = nt * nt, r2 = nr * nr;
        float pt = fp * d_ht;
        float pr = fp * d_hr;

        // hyper_tail = p (+) ft*t
        float ntc = fmaxf(nt, MIN_NORM);
        float xt  = fminf(hl * ntc, TANH_CLIP);
        float et  = __expf(-2.0f * xt);
        float ft  = (1.0f - et) * frcp((1.0f + et) * ntc);
        float yt2 = ft * ft * t2;
        float pyt = ft * pt;
        float invt = frcp(fmaxf(1.0f + 2.0f * pyt + p2 * yt2, MIN_NORM));
        float At = (1.0f + 2.0f * pyt + yt2) * invt;
        float Bt = tol * invt * ft;
        float x2 = (p2 + 2.0f * pyt + yt2) * invt;   // |ht|^2

        // hyper_rel = p (+) fr*r
        float nrc = fmaxf(nr, MIN_NORM);
        float xr  = fminf(hl * nrc, TANH_CLIP);
        float er  = __expf(-2.0f * xr);
        float fr  = (1.0f - er) * frcp((1.0f + er) * nrc);
        float yr2 = fr * fr * r2;
        float pyr = fr * pr;
        float invr = frcp(fmaxf(1.0f + 2.0f * pyr + p2 * yr2, MIN_NORM));
        float Ar = (1.0f + 2.0f * pyr + yr2) * invr;
        float Br = tol * invr * fr;
        float y2 = (p2 + 2.0f * pyr + yr2) * invr;   // |hr|^2

        // m = ht (+) hr
        float xy = At * Ar * p2 + At * Br * pr + Ar * Bt * pt + Bt * Br * d_tr;
        float am = 1.0f + 2.0f * xy + y2;
        float bm = 1.0f - x2;
        float invm = frcp(fmaxf(1.0f + 2.0f * xy + x2 * y2, MIN_NORM));
        float al = (am * At + bm * Ar) * invm;
        float be = am * Bt * invm;
        float ga = bm * Br * invm;
        float m2 = (x2 + 2.0f * xy + y2) * invm;     // |m|^2
        m2 = fmaxf(m2, 1e-30f);

        // project
        float scp = (m2 > MAXNORM2) ? MAXNORM * frsq(m2) : 1.0f;
        al *= scp; be *= scp; ga *= scp;
        m2 *= scp * scp;

        // s = (-p) (+) m
        float pm   = al * p2 + be * pt + ga * pr;
        float invs = frcp(fmaxf(1.0f - 2.0f * pm + p2 * m2, MIN_NORM));
        float sp   = -(1.0f - 2.0f * pm + m2) * invs;
        float smm  = tol * invs;
        float u = sp + smm * al;
        float v = smm * be;
        float w = smm * ga;
        float s2 = (p2 - 2.0f * pm + m2) * invs;     // |s|^2
        s2 = fmaxf(s2, 1e-30f);

        float irs = frsq(s2);
        float ns  = fminf(s2 * irs, 1.0f - 1e-7f);
        float art = 0.5f * __logf((1.0f + ns) * frcp(1.0f - ns));
        float sc  = tol * art * irs;

        float ct = sc * v, cr = sc * w;
        accP += sc * u;
        a0.x += ct * t0.x + cr * r0.x;  a0.y += ct * t0.y + cr * r0.y;
        a0.z += ct * t0.z + cr * r0.z;  a0.w += ct * t0.w + cr * r0.w;
        a1.x += ct * t1.x + cr * r1.x;  a1.y += ct * t1.y + cr * r1.y;
        a1.z += ct * t1.z + cr * r1.z;  a1.w += ct * t1.w + cr * r1.w;

        // ---- rotate pipeline ----
        i = inext; act = actn;
        t0 = pt0; t1 = pt1; r0 = pr0; r1 = pr1; nt = ntn; nr = nrn;
    }

    // reduce the 8 slots (lanes l, l^8, l^16, l^32)
    #define RED(x) x += __shfl_xor(x, 8); x += __shfl_xor(x, 16); x += __shfl_xor(x, 32);
    RED(accP)
    RED(a0.x) RED(a0.y) RED(a0.z) RED(a0.w)
    RED(a1.x) RED(a1.y) RED(a1.z) RED(a1.w)
    #undef RED

    if (slot == 0) {
        float invc = frcp(fmaxf((float)c, 1.0f));
        float hp = accP * fp * invc;               // p-coeff back to h-units
        f4 o0, o1;
        o0.x = hp * h0.x + a0.x * invc;  o0.y = hp * h0.y + a0.y * invc;
        o0.z = hp * h0.z + a0.z * invc;  o0.w = hp * h0.w + a0.w * invc;
        o1.x = hp * h1.x + a1.x * invc;  o1.y = hp * h1.y + a1.y * invc;
        o1.z = hp * h1.z + a1.z * invc;  o1.w = hp * h1.w + a1.w * invc;
        float* orow = out + (size_t)h * D + sub * 8;
        *(f4*)(orow)     = o0;
        *(f4*)(orow + 4) = o1;
    }
}

extern "C" void kernel_launch(void* const* d_in, const int* in_sizes, int n_in,
                              void* d_out, int out_size, void* d_ws, size_t ws_size,
                              hipStream_t stream) {
    const float* ego  = (const float*)d_in[0];
    const int*   eidx = (const int*)d_in[1];
    const int*   etyp = (const int*)d_in[2];
    const float* rel  = (const float*)d_in[3];
    float* out = (float*)d_out;

    int E = in_sizes[1] / 2;          // 800000
    int N = in_sizes[0] / D;          // 100000
    int NB = (N + CHUNK - 1) / CHUNK;

    // workspace layout (~7.6 MB)
    int* cnt      = (int*)d_ws;           // N
    int* off      = cnt + N;              // N
    int* rank     = off + N;              // E
    int* sorted   = rank + E;             // E
    float* norms   = (float*)(sorted + E);     // N
    float* relnorm = norms + N;                // 32

    hipMemsetAsync(cnt, 0, (size_t)N * sizeof(int), stream);

    const int tpb = 256;
    int hist_blocks = (E + tpb - 1) / tpb;
    int norm_blocks = (N + 32 + 3) / 4;

    hist_kernel<<<hist_blocks, tpb, 0, stream>>>(eidx, cnt, rank, E);
    scan_kernel<<<NB + norm_blocks, tpb, 0, stream>>>(cnt, off, ego, rel,
                                                      norms, relnorm, N, NB);
    scatter_kernel<<<hist_blocks, tpb, 0, stream>>>(eidx, etyp, rank, off, sorted, E);

    int nblocks = (N + 3) / 4;            // 4 waves (heads) per 256-block
    agg_kernel<<<nblocks, tpb, 0, stream>>>(ego, rel, off, cnt, sorted,
                                            norms, relnorm, out, N);
}

// Round 9
// 166.980 us; speedup vs baseline: 2.6880x; 1.0274x over previous
//
#include <hip/hip_runtime.h>
#include <math.h>

#define D 64
#define MAXNORM 0.999f
#define MAXNORM2 (0.999f * 0.999f)
#define MIN_NORM 1e-15f
#define TANH_CLIP 15.0f
#define CHUNK 1024

struct f4 { float x, y, z, w; };

__device__ __forceinline__ float frcp(float x) { return __builtin_amdgcn_rcpf(x); }
__device__ __forceinline__ float frsq(float x) { return __builtin_amdgcn_rsqf(x); }

__device__ __forceinline__ float dot8p(const f4& a0, const f4& a1,
                                       const f4& b0, const f4& b1) {
    return a0.x * b0.x + a0.y * b0.y + a0.z * b0.z + a0.w * b0.w +
           a1.x * b1.x + a1.y * b1.y + a1.z * b1.z + a1.w * b1.w;
}

__device__ __forceinline__ float rsum8(float v) {
    v += __shfl_xor(v, 1);
    v += __shfl_xor(v, 2);
    v += __shfl_xor(v, 4);
    return v;
}

// ------- histogram + per-edge rank -------

__global__ void hist_kernel(const int* __restrict__ eidx,
                            int* __restrict__ cnt,
                            int* __restrict__ rank, int E) {
    int e = blockIdx.x * blockDim.x + threadIdx.x;
    if (e < E) rank[e] = atomicAdd(&cnt[eidx[e]], 1);
}

// ------- scan (blocks [0,NB)) + row norms & head scalars (blocks [NB,..)) -------

__global__ void scan_kernel(const int* __restrict__ cnt,
                            int* __restrict__ off,
                            const float* __restrict__ ego,
                            const float* __restrict__ rel,
                            float* __restrict__ norms,
                            float* __restrict__ relnorm,
                            float2* __restrict__ scal,
                            int N, int NB, int E) {
    if (blockIdx.x >= NB) {
        // ---- norm + head-scalar part: one wave per row ----
        int wid = (blockIdx.x - NB) * 4 + (threadIdx.x >> 6);
        int lane = threadIdx.x & 63;
        if (wid >= N + 32) return;
        const float* src = (wid < N) ? (ego + (size_t)wid * D)
                                     : (rel + (size_t)(wid - N) * D);
        float v = src[lane];
        float s = v * v;
        s += __shfl_xor(s, 1);  s += __shfl_xor(s, 2);  s += __shfl_xor(s, 4);
        s += __shfl_xor(s, 8);  s += __shfl_xor(s, 16); s += __shfl_xor(s, 32);
        if (lane == 0) {
            float nh = sqrtf(s);
            if (wid < N) {
                norms[wid] = nh;
                float nhc = fmaxf(nh, MIN_NORM);
                float eh  = __expf(-2.0f * fminf(nhc, TANH_CLIP));
                float fp  = (1.0f - eh) * frcp((1.0f + eh) * nhc); // p = fp*h
                float th2 = fp * fp * nhc * nhc;                   // tanh^2
                float tol = fmaxf(1.0f - th2, MIN_NORM);           // 2/lam
                scal[wid] = make_float2(fp, tol);
            } else {
                relnorm[wid - N] = nh;
            }
        }
        return;
    }

    __shared__ int sdata[256];
    __shared__ int sprefix;
    int tid = threadIdx.x;
    int base0 = blockIdx.x * CHUNK;

    if (blockIdx.x == 0 && tid == 0) off[N] = E;

    // phase A: prefix = sum of cnt[0..base0)
    int psum = 0;
    const int4* cnt4 = (const int4*)cnt;
    for (int i = tid; i < (base0 >> 2); i += 256) {
        int4 v = cnt4[i];
        psum += v.x + v.y + v.z + v.w;
    }
    sdata[tid] = psum;
    __syncthreads();
    for (int o = 128; o > 0; o >>= 1) {
        if (tid < o) sdata[tid] += sdata[tid + o];
        __syncthreads();
    }
    if (tid == 0) sprefix = sdata[0];
    __syncthreads();
    int prefix = sprefix;
    __syncthreads();

    // phase B: scan own 1024-entry chunk
    int base = base0 + tid * 4;
    int v0 = (base + 0 < N) ? cnt[base + 0] : 0;
    int v1 = (base + 1 < N) ? cnt[base + 1] : 0;
    int v2 = (base + 2 < N) ? cnt[base + 2] : 0;
    int v3 = (base + 3 < N) ? cnt[base + 3] : 0;
    sdata[tid] = v0 + v1 + v2 + v3;
    __syncthreads();
    for (int o = 1; o < 256; o <<= 1) {
        int add = (tid >= o) ? sdata[tid - o] : 0;
        __syncthreads();
        sdata[tid] += add;
        __syncthreads();
    }
    int run = prefix + ((tid > 0) ? sdata[tid - 1] : 0);
    if (base + 0 < N) { off[base + 0] = run; run += v0; }
    if (base + 1 < N) { off[base + 1] = run; run += v1; }
    if (base + 2 < N) { off[base + 2] = run; run += v2; }
    if (base + 3 < N) { off[base + 3] = run; run += v3; }
}

// atomic-free scatter: pos = off[head] + rank[e]; payload = tail | type<<17
__global__ void scatter_kernel(const int* __restrict__ eidx,
                               const int* __restrict__ etype,
                               const int* __restrict__ rank,
                               const int* __restrict__ off,
                               int* __restrict__ sorted, int E) {
    int e = blockIdx.x * blockDim.x + threadIdx.x;
    if (e < E) {
        int pos = off[eidx[e]] + rank[e];
        sorted[pos] = eidx[E + e] | (etype[e] << 17);
    }
}

// ---------------- segmented aggregation: one wave per head ----------------
// Per-edge geometry is scalar algebra over 3 dots (h.t, h.r, t.r); norms of
// Mobius sums via |x(+)y|^2 = (|x|^2 + 2 x.y + |y|^2) * inv_den and the
// coefficient identities x2=(at-tol)*invt, m2=(am-bm)*invm, s2=(om-tol)*invs.

__global__ void __launch_bounds__(256) agg_kernel(
        const float* __restrict__ ego,
        const float* __restrict__ rel,
        const int* __restrict__ off,
        const int* __restrict__ sorted,
        const float* __restrict__ norms,
        const float* __restrict__ relnorm,
        const float2* __restrict__ scal,
        float* __restrict__ out,
        int N) {
    int wid = (blockIdx.x * blockDim.x + threadIdx.x) >> 6;   // one wave per head
    if (wid >= N) return;
    int lane = threadIdx.x & 63;
    int slot = lane >> 3;     // 8 edge-slots per wave
    int sub  = lane & 7;      // 8 lanes per edge, 8 comps each

    int h = wid;
    const float* hrow = ego + (size_t)h * D + sub * 8;
    f4 h0 = *(const f4*)(hrow);
    f4 h1 = *(const f4*)(hrow + 4);

    // head-only scalars (precomputed in scan_kernel)
    float2 sc2 = scal[h];
    float fp  = sc2.x;                 // p = fp * h
    float tol = sc2.y;                 // 2/lam = 1 - tanh^2
    float p2  = 1.0f - tol;            // tanh^2
    float hl  = frcp(tol);             // 0.5*lam

    int o = off[h];
    int c = off[h + 1] - o;
    f4 a0 = {0.f, 0.f, 0.f, 0.f}, a1 = {0.f, 0.f, 0.f, 0.f};
    float accP = 0.f;

    for (int i = slot; i < c; i += 8) {
        int pk   = sorted[o + i];
        int tail = pk & 0x1FFFF;
        int type = pk >> 17;

        const float* trow = ego + (size_t)tail * D + sub * 8;
        f4 t0 = *(const f4*)(trow);
        f4 t1 = *(const f4*)(trow + 4);
        const float* rrow = rel + (size_t)type * D + sub * 8;
        f4 r0 = *(const f4*)(rrow);
        f4 r1 = *(const f4*)(rrow + 4);
        float nt = norms[tail];
        float nr = relnorm[type];

        // the only 3 wave reductions per edge
        float d_ht = rsum8(dot8p(h0, h1, t0, t1));
        float d_hr = rsum8(dot8p(h0, h1, r0, r1));
        float d_tr = rsum8(dot8p(t0, t1, r0, r1));

        float t2 = nt * nt, r2 = nr * nr;
        float pt = fp * d_ht;
        float pr = fp * d_hr;

        // hyper_tail = p (+) ft*t
        float ntc = fmaxf(nt, MIN_NORM);
        float et  = __expf(-2.0f * fminf(hl * ntc, TANH_CLIP));
        float ft  = (1.0f - et) * frcp((1.0f + et) * ntc);
        float pyt = ft * pt;
        float yt2 = ft * ft * t2;
        float o1t = fmaf(2.0f, pyt, 1.0f);                 // 1+2p.yt
        float at  = o1t + yt2;
        float invt = frcp(fmaxf(fmaf(p2, yt2, o1t), MIN_NORM));
        float At = at * invt;
        float Bt = tol * invt * ft;
        float x2 = (at - tol) * invt;                      // |ht|^2

        // hyper_rel = p (+) fr*r
        float nrc = fmaxf(nr, MIN_NORM);
        float er  = __expf(-2.0f * fminf(hl * nrc, TANH_CLIP));
        float fr  = (1.0f - er) * frcp((1.0f + er) * nrc);
        float pyr = fr * pr;
        float yr2 = fr * fr * r2;
        float o1r = fmaf(2.0f, pyr, 1.0f);
        float ar  = o1r + yr2;
        float invr = frcp(fmaxf(fmaf(p2, yr2, o1r), MIN_NORM));
        float Ar = ar * invr;
        float Br = tol * invr * fr;
        float y2 = (ar - tol) * invr;                      // |hr|^2

        // m = ht (+) hr
        float xy = At * Ar * p2 + At * Br * pr + Ar * Bt * pt + Bt * Br * d_tr;
        float o1m = fmaf(2.0f, xy, 1.0f);
        float am = o1m + y2;
        float bm = 1.0f - x2;
        float invm = frcp(fmaxf(fmaf(x2, y2, o1m), MIN_NORM));
        float al = (am * At + bm * Ar) * invm;
        float be = am * Bt * invm;
        float ga = bm * Br * invm;
        float m2 = fmaxf((am - bm) * invm, 1e-30f);        // |m|^2

        // project
        if (m2 > MAXNORM2) {
            float s_ = MAXNORM * frsq(m2);
            al *= s_; be *= s_; ga *= s_;
            m2 = MAXNORM2;
        }

        // s = (-p) (+) m
        float pm   = al * p2 + be * pt + ga * pr;
        float o2   = fmaf(-2.0f, pm, 1.0f);                // 1-2p.m
        float invs = frcp(fmaxf(fmaf(p2, m2, o2), MIN_NORM));
        float om   = o2 + m2;
        float smm  = tol * invs;
        float u = fmaf(smm, al, -om * invs);
        float v = smm * be;
        float w = smm * ga;
        float s2 = fmaxf((om - tol) * invs, 1e-30f);       // |s|^2

        float irs = frsq(s2);
        float ns  = fminf(s2 * irs, 1.0f - 1e-7f);
        float art = 0.5f * __logf((1.0f + ns) * frcp(1.0f - ns));
        float scv = tol * art * irs;                       // (2/lam)*artanh/|s|

        float ct = scv * v, cr = scv * w;
        accP = fmaf(scv, u, accP);
        a0.x += ct * t0.x + cr * r0.x;  a0.y += ct * t0.y + cr * r0.y;
        a0.z += ct * t0.z + cr * r0.z;  a0.w += ct * t0.w + cr * r0.w;
        a1.x += ct * t1.x + cr * r1.x;  a1.y += ct * t1.y + cr * r1.y;
        a1.z += ct * t1.z + cr * r1.z;  a1.w += ct * t1.w + cr * r1.w;
    }

    // reduce the 8 slots (lanes l, l^8, l^16, l^32)
    #define RED(x) x += __shfl_xor(x, 8); x += __shfl_xor(x, 16); x += __shfl_xor(x, 32);
    RED(accP)
    RED(a0.x) RED(a0.y) RED(a0.z) RED(a0.w)
    RED(a1.x) RED(a1.y) RED(a1.z) RED(a1.w)
    #undef RED

    if (slot == 0) {
        float invc = frcp(fmaxf((float)c, 1.0f));
        float hp = accP * fp * invc;               // p-coeff back to h-units
        f4 o0, o1;
        o0.x = hp * h0.x + a0.x * invc;  o0.y = hp * h0.y + a0.y * invc;
        o0.z = hp * h0.z + a0.z * invc;  o0.w = hp * h0.w + a0.w * invc;
        o1.x = hp * h1.x + a1.x * invc;  o1.y = hp * h1.y + a1.y * invc;
        o1.z = hp * h1.z + a1.z * invc;  o1.w = hp * h1.w + a1.w * invc;
        float* orow = out + (size_t)h * D + sub * 8;
        *(f4*)(orow)     = o0;
        *(f4*)(orow + 4) = o1;
    }
}

extern "C" void kernel_launch(void* const* d_in, const int* in_sizes, int n_in,
                              void* d_out, int out_size, void* d_ws, size_t ws_size,
                              hipStream_t stream) {
    const float* ego  = (const float*)d_in[0];
    const int*   eidx = (const int*)d_in[1];
    const int*   etyp = (const int*)d_in[2];
    const float* rel  = (const float*)d_in[3];
    float* out = (float*)d_out;

    int E = in_sizes[1] / 2;          // 800000
    int N = in_sizes[0] / D;          // 100000
    int NB = (N + CHUNK - 1) / CHUNK;

    // workspace layout (~8.4 MB); scal first for 8B alignment
    float2* scal  = (float2*)d_ws;              // N float2
    int* cnt      = (int*)(scal + N);           // N
    int* off      = cnt + N;                    // N+1
    int* rank     = off + N + 1;                // E
    int* sorted   = rank + E;                   // E
    float* norms   = (float*)(sorted + E);      // N
    float* relnorm = norms + N;                 // 32

    hipMemsetAsync(cnt, 0, (size_t)N * sizeof(int), stream);

    const int tpb = 256;
    int hist_blocks = (E + tpb - 1) / tpb;
    int norm_blocks = (N + 32 + 3) / 4;

    hist_kernel<<<hist_blocks, tpb, 0, stream>>>(eidx, cnt, rank, E);
    scan_kernel<<<NB + norm_blocks, tpb, 0, stream>>>(cnt, off, ego, rel,
                                                      norms, relnorm, scal,
                                                      N, NB, E);
    scatter_kernel<<<hist_blocks, tpb, 0, stream>>>(eidx, etyp, rank, off, sorted, E);

    int nblocks = (N + 3) / 4;            // 4 waves (heads) per 256-block
    agg_kernel<<<nblocks, tpb, 0, stream>>>(ego, rel, off, sorted,
                                            norms, relnorm, scal, out, N);
}

// Round 10
// 166.388 us; speedup vs baseline: 2.6976x; 1.0036x over previous
//
#include <hip/hip_runtime.h>
#include <math.h>

#define D 64
#define MAXNORM 0.999f
#define MAXNORM2 (0.999f * 0.999f)
#define MIN_NORM 1e-15f
#define TANH_CLIP 15.0f
#define CHUNK 1024

struct f4 { float x, y, z, w; };

__device__ __forceinline__ float frcp(float x) { return __builtin_amdgcn_rcpf(x); }
__device__ __forceinline__ float frsq(float x) { return __builtin_amdgcn_rsqf(x); }

__device__ __forceinline__ float dot8p(const f4& a0, const f4& a1,
                                       const f4& b0, const f4& b1) {
    return a0.x * b0.x + a0.y * b0.y + a0.z * b0.z + a0.w * b0.w +
           a1.x * b1.x + a1.y * b1.y + a1.z * b1.z + a1.w * b1.w;
}

__device__ __forceinline__ float rsum8(float v) {
    v += __shfl_xor(v, 1);
    v += __shfl_xor(v, 2);
    v += __shfl_xor(v, 4);
    return v;
}

// ------- histogram + per-edge rank -------

__global__ void hist_kernel(const int* __restrict__ eidx,
                            int* __restrict__ cnt,
                            int* __restrict__ rank, int E) {
    int e = blockIdx.x * blockDim.x + threadIdx.x;
    if (e < E) rank[e] = atomicAdd(&cnt[eidx[e]], 1);
}

// ------- scan (blocks [0,NB)) + row norms & head scalars (blocks [NB,..)) -------

__global__ void scan_kernel(const int* __restrict__ cnt,
                            int* __restrict__ off,
                            const float* __restrict__ ego,
                            const float* __restrict__ rel,
                            float* __restrict__ norms,
                            float* __restrict__ relnorm,
                            float2* __restrict__ scal,
                            int N, int NB, int E) {
    if (blockIdx.x >= NB) {
        // ---- norm + head-scalar part: one wave per row ----
        int wid = (blockIdx.x - NB) * 4 + (threadIdx.x >> 6);
        int lane = threadIdx.x & 63;
        if (wid >= N + 32) return;
        const float* src = (wid < N) ? (ego + (size_t)wid * D)
                                     : (rel + (size_t)(wid - N) * D);
        float v = src[lane];
        float s = v * v;
        s += __shfl_xor(s, 1);  s += __shfl_xor(s, 2);  s += __shfl_xor(s, 4);
        s += __shfl_xor(s, 8);  s += __shfl_xor(s, 16); s += __shfl_xor(s, 32);
        if (lane == 0) {
            float nh = sqrtf(s);
            if (wid < N) {
                norms[wid] = nh;
                float nhc = fmaxf(nh, MIN_NORM);
                float eh  = __expf(-2.0f * fminf(nhc, TANH_CLIP));
                float fp  = (1.0f - eh) * frcp((1.0f + eh) * nhc); // p = fp*h
                float th2 = fp * fp * nhc * nhc;                   // tanh^2
                float tol = fmaxf(1.0f - th2, MIN_NORM);           // 2/lam
                scal[wid] = make_float2(fp, tol);
            } else {
                relnorm[wid - N] = nh;
            }
        }
        return;
    }

    __shared__ int sdata[256];
    __shared__ int sprefix;
    int tid = threadIdx.x;
    int base0 = blockIdx.x * CHUNK;

    if (blockIdx.x == 0 && tid == 0) off[N] = E;

    // phase A: prefix = sum of cnt[0..base0)
    int psum = 0;
    const int4* cnt4 = (const int4*)cnt;
    for (int i = tid; i < (base0 >> 2); i += 256) {
        int4 v = cnt4[i];
        psum += v.x + v.y + v.z + v.w;
    }
    sdata[tid] = psum;
    __syncthreads();
    for (int o = 128; o > 0; o >>= 1) {
        if (tid < o) sdata[tid] += sdata[tid + o];
        __syncthreads();
    }
    if (tid == 0) sprefix = sdata[0];
    __syncthreads();
    int prefix = sprefix;
    __syncthreads();

    // phase B: scan own 1024-entry chunk
    int base = base0 + tid * 4;
    int v0 = (base + 0 < N) ? cnt[base + 0] : 0;
    int v1 = (base + 1 < N) ? cnt[base + 1] : 0;
    int v2 = (base + 2 < N) ? cnt[base + 2] : 0;
    int v3 = (base + 3 < N) ? cnt[base + 3] : 0;
    sdata[tid] = v0 + v1 + v2 + v3;
    __syncthreads();
    for (int o = 1; o < 256; o <<= 1) {
        int add = (tid >= o) ? sdata[tid - o] : 0;
        __syncthreads();
        sdata[tid] += add;
        __syncthreads();
    }
    int run = prefix + ((tid > 0) ? sdata[tid - 1] : 0);
    if (base + 0 < N) { off[base + 0] = run; run += v0; }
    if (base + 1 < N) { off[base + 1] = run; run += v1; }
    if (base + 2 < N) { off[base + 2] = run; run += v2; }
    if (base + 3 < N) { off[base + 3] = run; run += v3; }
}

// atomic-free scatter: pos = off[head] + rank[e]; payload = tail | type<<17
__global__ void scatter_kernel(const int* __restrict__ eidx,
                               const int* __restrict__ etype,
                               const int* __restrict__ rank,
                               const int* __restrict__ off,
                               int* __restrict__ sorted, int E) {
    int e = blockIdx.x * blockDim.x + threadIdx.x;
    if (e < E) {
        int pos = off[eidx[e]] + rank[e];
        sorted[pos] = eidx[E + e] | (etype[e] << 17);
    }
}

// ---------------- segmented aggregation: one wave per head ----------------
// Per-edge geometry is scalar algebra over 3 dots (h.t, h.r, t.r); norms of
// Mobius sums via coefficient identities. Lane<->component mapping is BLOCKED:
// lane sub holds comps [sub*4, sub*4+4) and [32+sub*4, 32+sub*4+4), so each
// 64-lane load instruction covers contiguous 128B half-rows (2 cache lines
// per row instead of 4 -> half the TA/L1 line requests per gather).

__global__ void __launch_bounds__(256) agg_kernel(
        const float* __restrict__ ego,
        const float* __restrict__ rel,
        const int* __restrict__ off,
        const int* __restrict__ sorted,
        const float* __restrict__ norms,
        const float* __restrict__ relnorm,
        const float2* __restrict__ scal,
        float* __restrict__ out,
        int N) {
    int wid = (blockIdx.x * blockDim.x + threadIdx.x) >> 6;   // one wave per head
    if (wid >= N) return;
    int lane = threadIdx.x & 63;
    int slot = lane >> 3;     // 8 edge-slots per wave
    int sub  = lane & 7;      // 8 lanes per edge, blocked comps

    int h = wid;
    const float* hrow = ego + (size_t)h * D;
    f4 h0 = *(const f4*)(hrow + sub * 4);
    f4 h1 = *(const f4*)(hrow + 32 + sub * 4);

    // head-only scalars (precomputed in scan_kernel)
    float2 sc2 = scal[h];
    float fp  = sc2.x;                 // p = fp * h
    float tol = sc2.y;                 // 2/lam = 1 - tanh^2
    float p2  = 1.0f - tol;            // tanh^2
    float hl  = frcp(tol);             // 0.5*lam

    int o = off[h];
    int c = off[h + 1] - o;
    f4 a0 = {0.f, 0.f, 0.f, 0.f}, a1 = {0.f, 0.f, 0.f, 0.f};
    float accP = 0.f;

    for (int i = slot; i < c; i += 8) {
        int pk   = sorted[o + i];
        int tail = pk & 0x1FFFF;
        int type = pk >> 17;

        const float* trow = ego + (size_t)tail * D;
        f4 t0 = *(const f4*)(trow + sub * 4);
        f4 t1 = *(const f4*)(trow + 32 + sub * 4);
        const float* rrow = rel + (size_t)type * D;
        f4 r0 = *(const f4*)(rrow + sub * 4);
        f4 r1 = *(const f4*)(rrow + 32 + sub * 4);
        float nt = norms[tail];
        float nr = relnorm[type];

        // the only 3 wave reductions per edge
        float d_ht = rsum8(dot8p(h0, h1, t0, t1));
        float d_hr = rsum8(dot8p(h0, h1, r0, r1));
        float d_tr = rsum8(dot8p(t0, t1, r0, r1));

        float t2 = nt * nt, r2 = nr * nr;
        float pt = fp * d_ht;
        float pr = fp * d_hr;

        // hyper_tail = p (+) ft*t
        float ntc = fmaxf(nt, MIN_NORM);
        float et  = __expf(-2.0f * fminf(hl * ntc, TANH_CLIP));
        float ft  = (1.0f - et) * frcp((1.0f + et) * ntc);
        float pyt = ft * pt;
        float yt2 = ft * ft * t2;
        float o1t = fmaf(2.0f, pyt, 1.0f);                 // 1+2p.yt
        float at  = o1t + yt2;
        float invt = frcp(fmaxf(fmaf(p2, yt2, o1t), MIN_NORM));
        float At = at * invt;
        float Bt = tol * invt * ft;
        float x2 = (at - tol) * invt;                      // |ht|^2

        // hyper_rel = p (+) fr*r
        float nrc = fmaxf(nr, MIN_NORM);
        float er  = __expf(-2.0f * fminf(hl * nrc, TANH_CLIP));
        float fr  = (1.0f - er) * frcp((1.0f + er) * nrc);
        float pyr = fr * pr;
        float yr2 = fr * fr * r2;
        float o1r = fmaf(2.0f, pyr, 1.0f);
        float ar  = o1r + yr2;
        float invr = frcp(fmaxf(fmaf(p2, yr2, o1r), MIN_NORM));
        float Ar = ar * invr;
        float Br = tol * invr * fr;
        float y2 = (ar - tol) * invr;                      // |hr|^2

        // m = ht (+) hr
        float xy = At * Ar * p2 + At * Br * pr + Ar * Bt * pt + Bt * Br * d_tr;
        float o1m = fmaf(2.0f, xy, 1.0f);
        float am = o1m + y2;
        float bm = 1.0f - x2;
        float invm = frcp(fmaxf(fmaf(x2, y2, o1m), MIN_NORM));
        float al = (am * At + bm * Ar) * invm;
        float be = am * Bt * invm;
        float ga = bm * Br * invm;
        float m2 = fmaxf((am - bm) * invm, 1e-30f);        // |m|^2

        // project
        if (m2 > MAXNORM2) {
            float s_ = MAXNORM * frsq(m2);
            al *= s_; be *= s_; ga *= s_;
            m2 = MAXNORM2;
        }

        // s = (-p) (+) m
        float pm   = al * p2 + be * pt + ga * pr;
        float o2   = fmaf(-2.0f, pm, 1.0f);                // 1-2p.m
        float invs = frcp(fmaxf(fmaf(p2, m2, o2), MIN_NORM));
        float om   = o2 + m2;
        float smm  = tol * invs;
        float u = fmaf(smm, al, -om * invs);
        float v = smm * be;
        float w = smm * ga;
        float s2 = fmaxf((om - tol) * invs, 1e-30f);       // |s|^2

        float irs = frsq(s2);
        float ns  = fminf(s2 * irs, 1.0f - 1e-7f);
        float art = 0.5f * __logf((1.0f + ns) * frcp(1.0f - ns));
        float scv = tol * art * irs;                       // (2/lam)*artanh/|s|

        float ct = scv * v, cr = scv * w;
        accP = fmaf(scv, u, accP);
        a0.x += ct * t0.x + cr * r0.x;  a0.y += ct * t0.y + cr * r0.y;
        a0.z += ct * t0.z + cr * r0.z;  a0.w += ct * t0.w + cr * r0.w;
        a1.x += ct * t1.x + cr * r1.x;  a1.y += ct * t1.y + cr * r1.y;
        a1.z += ct * t1.z + cr * r1.z;  a1.w += ct * t1.w + cr * r1.w;
    }

    // reduce the 8 slots (lanes l, l^8, l^16, l^32); comp-set depends only on
    // sub = lane&7, which is invariant under these XORs -> mapping-safe.
    #define RED(x) x += __shfl_xor(x, 8); x += __shfl_xor(x, 16); x += __shfl_xor(x, 32);
    RED(accP)
    RED(a0.x) RED(a0.y) RED(a0.z) RED(a0.w)
    RED(a1.x) RED(a1.y) RED(a1.z) RED(a1.w)
    #undef RED

    if (slot == 0) {
        float invc = frcp(fmaxf((float)c, 1.0f));
        float hp = accP * fp * invc;               // p-coeff back to h-units
        f4 o0, o1;
        o0.x = hp * h0.x + a0.x * invc;  o0.y = hp * h0.y + a0.y * invc;
        o0.z = hp * h0.z + a0.z * invc;  o0.w = hp * h0.w + a0.w * invc;
        o1.x = hp * h1.x + a1.x * invc;  o1.y = hp * h1.y + a1.y * invc;
        o1.z = hp * h1.z + a1.z * invc;  o1.w = hp * h1.w + a1.w * invc;
        float* orow = out + (size_t)h * D;
        *(f4*)(orow + sub * 4)      = o0;
        *(f4*)(orow + 32 + sub * 4) = o1;
    }
}

extern "C" void kernel_launch(void* const* d_in, const int* in_sizes, int n_in,
                              void* d_out, int out_size, void* d_ws, size_t ws_size,
                              hipStream_t stream) {
    const float* ego  = (const float*)d_in[0];
    const int*   eidx = (const int*)d_in[1];
    const int*   etyp = (const int*)d_in[2];
    const float* rel  = (const float*)d_in[3];
    float* out = (float*)d_out;

    int E = in_sizes[1] / 2;          // 800000
    int N = in_sizes[0] / D;          // 100000
    int NB = (N + CHUNK - 1) / CHUNK;

    // workspace layout (~8.4 MB); scal first for 8B alignment
    float2* scal  = (float2*)d_ws;              // N float2
    int* cnt      = (int*)(scal + N);           // N
    int* off      = cnt + N;                    // N+1
    int* rank     = off + N + 1;                // E
    int* sorted   = rank + E;                   // E
    float* norms   = (float*)(sorted + E);      // N
    float* relnorm = norms + N;                 // 32

    hipMemsetAsync(cnt, 0, (size_t)N * sizeof(int), stream);

    const int tpb = 256;
    int hist_blocks = (E + tpb - 1) / tpb;
    int norm_blocks = (N + 32 + 3) / 4;

    hist_kernel<<<hist_blocks, tpb, 0, stream>>>(eidx, cnt, rank, E);
    scan_kernel<<<NB + norm_blocks, tpb, 0, stream>>>(cnt, off, ego, rel,
                                                      norms, relnorm, scal,
                                                      N, NB, E);
    scatter_kernel<<<hist_blocks, tpb, 0, stream>>>(eidx, etyp, rank, off, sorted, E);

    int nblocks = (N + 3) / 4;            // 4 waves (heads) per 256-block
    agg_kernel<<<nblocks, tpb, 0, stream>>>(ego, rel, off, sorted,
                                            norms, relnorm, scal, out, N);
}